// Round 1
// baseline (431.918 us; speedup 1.0000x reference)
//
#include <hip/hip_runtime.h>
#include <stdint.h>

#define NLOC 469
#define NCLS 80
#define NFLAT 37520
#define TOPK 1000
#define NSLICE 16
#define SLICE_LEN 2345   // 16 * 2345 = 37520 exactly

__device__ __forceinline__ float sigm(float x) { return 1.0f / (1.0f + expf(-x)); }

// order-preserving float -> uint32 (greater float => greater uint)
__device__ __forceinline__ uint32_t f2o(float f) {
    uint32_t u = __float_as_uint(f);
    return (u & 0x80000000u) ? ~u : (u | 0x80000000u);
}

__global__ void decode_kernel(
    const float* __restrict__ s0, const float* __restrict__ l0, const float* __restrict__ c0,
    const float* __restrict__ s1, const float* __restrict__ l1, const float* __restrict__ c1,
    const float* __restrict__ s2, const float* __restrict__ l2, const float* __restrict__ c2,
    uint64_t* __restrict__ keys, float4* __restrict__ bbox)
{
    int t = blockIdx.x * blockDim.x + threadIdx.x;
    if (t < NFLAT) {
        int p = t / NCLS;
        int k = t - p * NCLS;
        int c = k + 1;                       // class channel (0 = background, dropped)
        const float* sr; const float* cr; int local, hw;
        if (p < 350)      { sr = s0; cr = c0; local = p;       hw = 350; }
        else if (p < 441) { sr = s1; cr = c1; local = p - 350; hw = 91;  }
        else              { sr = s2; cr = c2; local = p - 441; hw = 28;  }
        float val = sqrtf(sigm(sr[c * hw + local]) * sigm(cr[local]));
        float masked = (val >= 0.05f) ? val : -1.0f;
        // key: value-major, tie -> lower index wins (larger low word)
        keys[t] = ((uint64_t)f2o(masked) << 32) | (uint64_t)(0xFFFFFFFFu - (uint32_t)t);
    }
    if (t < NLOC) {
        int p = t;
        const float* lr; int local, hw, w; float is;
        if (p < 350)      { lr = l0; local = p;       hw = 350; w = 25; is = 16.0f; }
        else if (p < 441) { lr = l1; local = p - 350; hw = 91;  w = 13; is = 32.0f; }
        else              { lr = l2; local = p - 441; hw = 28;  w = 7;  is = 64.0f; }
        int y = local / w, x = local - y * w;
        // scale is an exact power of two -> multiply by inverse is bit-exact
        float px = ((float)x + 0.5f) * is;
        float py = ((float)y + 0.5f) * is;
        float L = lr[local] * is;
        float T = lr[hw + local] * is;
        float R = lr[2 * hw + local] * is;
        float B = lr[3 * hw + local] * is;
        bbox[p] = make_float4(px - L, py - T, px + R, py + B);
    }
}

// rank[i] = #keys strictly greater than key[i]; split over 16 j-slices for parallelism
__global__ void rank_kernel(const uint64_t* __restrict__ keys, int* __restrict__ rank)
{
    __shared__ uint64_t tile[256];
    int t = blockIdx.x * blockDim.x + threadIdx.x;
    uint64_t myk = (t < NFLAT) ? keys[t] : 0xFFFFFFFFFFFFFFFFull;
    int begin = blockIdx.y * SLICE_LEN;
    int end = begin + SLICE_LEN;           // always <= NFLAT by construction
    int cnt = 0;
    for (int base = begin; base < end; base += 256) {
        int j = base + threadIdx.x;
        tile[threadIdx.x] = (j < end) ? keys[j] : 0ull;
        __syncthreads();
        int lim = min(256, end - base);
        for (int q = 0; q < lim; ++q)
            cnt += (tile[q] > myk) ? 1 : 0;
        __syncthreads();
    }
    if (t < NFLAT && cnt > 0) atomicAdd(&rank[t], cnt);
}

__global__ void scatter_kernel(const uint64_t* __restrict__ keys, const int* __restrict__ rank,
                               float* __restrict__ top_val, int* __restrict__ top_idx)
{
    int t = blockIdx.x * blockDim.x + threadIdx.x;
    if (t >= NFLAT) return;
    int r = rank[t];
    if (r < TOPK) {
        uint64_t k = keys[t];
        uint32_t o = (uint32_t)(k >> 32);
        uint32_t u = (o & 0x80000000u) ? (o ^ 0x80000000u) : ~o;  // inverse of f2o
        top_val[r] = __uint_as_float(u);
        top_idx[r] = (int)(0xFFFFFFFFu - (uint32_t)(k & 0xFFFFFFFFu));
    }
}

__global__ void __launch_bounds__(1024) nms_kernel(
    const float* __restrict__ top_val, const int* __restrict__ top_idx,
    const float4* __restrict__ bbox, float* __restrict__ out)
{
    __shared__ float4 sb[TOPK];
    __shared__ float sarea[TOPK];
    __shared__ int skeep[TOPK];
    __shared__ float swave[16];
    int j = threadIdx.x;
    bool active = j < TOPK;
    float4 b = make_float4(0.f, 0.f, 0.f, 0.f);
    float tv = -1.0f; int lab = 0;
    if (active) {
        tv = top_val[j];
        int idx = top_idx[j];
        int p = idx / NCLS;
        lab = idx - p * NCLS;
        b = bbox[p];
    }
    // global max over all selected boxes' coords (invalid rows included, matching ref)
    float m = active ? fmaxf(fmaxf(b.x, b.y), fmaxf(b.z, b.w)) : -3.0e38f;
    for (int o = 32; o > 0; o >>= 1) m = fmaxf(m, __shfl_down(m, o, 64));
    if ((j & 63) == 0) swave[j >> 6] = m;
    __syncthreads();
    if (j == 0) {
        float mm = swave[0];
        for (int q = 1; q < 16; ++q) mm = fmaxf(mm, swave[q]);
        swave[0] = mm;
    }
    __syncthreads();
    float off = (float)lab * (swave[0] + 1.0f);
    float4 s = make_float4(b.x + off, b.y + off, b.z + off, b.w + off);
    float areaj = fmaxf(s.z - s.x, 0.f) * fmaxf(s.w - s.y, 0.f);
    if (active) {
        sb[j] = s;
        sarea[j] = areaj;
        skeep[j] = (tv >= 0.05f) ? 1 : 0;
    }
    __syncthreads();
    // greedy NMS: thread j owns box j; only thread j ever writes skeep[j]
    for (int i = 0; i < TOPK; ++i) {
        if (skeep[i]) {
            if (active && j > i && skeep[j]) {
                float4 bi = sb[i];
                float ltx = fmaxf(bi.x, s.x), lty = fmaxf(bi.y, s.y);
                float rbx = fminf(bi.z, s.z), rby = fminf(bi.w, s.w);
                float iw = fmaxf(rbx - ltx, 0.f), ih = fmaxf(rby - lty, 0.f);
                float inter = iw * ih;
                float iou = inter / fmaxf(sarea[i] + areaj - inter, 1e-9f);
                if (iou > 0.6f) skeep[j] = 0;
            }
        }
        __syncthreads();
    }
    if (active) {
        bool kp = skeep[j] != 0;
        // clip: x -> [0, 224] (MODEL_H), y -> [0, 398] (MODEL_W), per reference comment
        float x1 = fminf(fmaxf(b.x, 0.f), 224.f);
        float y1 = fminf(fmaxf(b.y, 0.f), 398.f);
        float x2 = fminf(fmaxf(b.z, 0.f), 224.f);
        float y2 = fminf(fmaxf(b.w, 0.f), 398.f);
        kp = kp && ((x2 - x1) >= 1e-5f) && ((y2 - y1) >= 1e-5f);
        out[j * 4 + 0] = kp ? x1 : 0.f;
        out[j * 4 + 1] = kp ? y1 : 0.f;
        out[j * 4 + 2] = kp ? x2 : 0.f;
        out[j * 4 + 3] = kp ? y2 : 0.f;
        out[4 * TOPK + j] = kp ? tv : -1.0f;
        out[5 * TOPK + j] = (float)lab;           // label emitted regardless of keep
        out[6 * TOPK + j] = kp ? 1.0f : 0.0f;     // keep as 0/1 float
    }
}

extern "C" void kernel_launch(void* const* d_in, const int* in_sizes, int n_in,
                              void* d_out, int out_size, void* d_ws, size_t ws_size,
                              hipStream_t stream)
{
    const float* s0 = (const float*)d_in[0];
    const float* l0 = (const float*)d_in[1];
    const float* c0 = (const float*)d_in[2];
    const float* s1 = (const float*)d_in[3];
    const float* l1 = (const float*)d_in[4];
    const float* c1 = (const float*)d_in[5];
    const float* s2 = (const float*)d_in[6];
    const float* l2 = (const float*)d_in[7];
    const float* c2 = (const float*)d_in[8];

    uint8_t* ws = (uint8_t*)d_ws;
    uint64_t* keys = (uint64_t*)(ws);            // 37520*8  = 300160 B
    float4*   bbox = (float4*)  (ws + 300160);   // 469*16   =   7504 B
    int*      rank = (int*)     (ws + 307664);   // 37520*4  = 150080 B
    float*    tval = (float*)   (ws + 457744);   // 1000*4
    int*      tidx = (int*)     (ws + 461744);   // 1000*4  -> 465744 B total

    hipMemsetAsync(rank, 0, NFLAT * sizeof(int), stream);
    decode_kernel<<<dim3((NFLAT + 255) / 256), 256, 0, stream>>>(
        s0, l0, c0, s1, l1, c1, s2, l2, c2, keys, bbox);
    rank_kernel<<<dim3((NFLAT + 255) / 256, NSLICE), 256, 0, stream>>>(keys, rank);
    scatter_kernel<<<dim3((NFLAT + 255) / 256), 256, 0, stream>>>(keys, rank, tval, tidx);
    nms_kernel<<<1, 1024, 0, stream>>>(tval, tidx, bbox, (float*)d_out);
}

// Round 3
// 213.016 us; speedup vs baseline: 2.0276x; 2.0276x over previous
//
#include <hip/hip_runtime.h>
#include <stdint.h>

#define NLOC 469
#define NCLS 80
#define NFLAT 37520
#define TOPK 1000
#define NSLICE 16
#define SLICE_LEN 2345   // 16 * 2345 = 37520 exactly
#define NWORD 16         // 1000 bits -> 16 uint64 words

typedef unsigned long long u64;

__device__ __forceinline__ float sigm(float x) { return 1.0f / (1.0f + expf(-x)); }

// order-preserving float -> uint32 (greater float => greater uint)
__device__ __forceinline__ uint32_t f2o(float f) {
    uint32_t u = __float_as_uint(f);
    return (u & 0x80000000u) ? ~u : (u | 0x80000000u);
}

__global__ void decode_kernel(
    const float* __restrict__ s0, const float* __restrict__ l0, const float* __restrict__ c0,
    const float* __restrict__ s1, const float* __restrict__ l1, const float* __restrict__ c1,
    const float* __restrict__ s2, const float* __restrict__ l2, const float* __restrict__ c2,
    u64* __restrict__ keys, float4* __restrict__ bbox, int* __restrict__ rank)
{
    int t = blockIdx.x * blockDim.x + threadIdx.x;
    if (t < NFLAT) {
        rank[t] = 0;                         // zero-init for rank_kernel's atomics
        int p = t / NCLS;
        int k = t - p * NCLS;
        int c = k + 1;                       // class channel (0 = background, dropped)
        const float* sr; const float* cr; int local, hw;
        if (p < 350)      { sr = s0; cr = c0; local = p;       hw = 350; }
        else if (p < 441) { sr = s1; cr = c1; local = p - 350; hw = 91;  }
        else              { sr = s2; cr = c2; local = p - 441; hw = 28;  }
        float val = sqrtf(sigm(sr[c * hw + local]) * sigm(cr[local]));
        float masked = (val >= 0.05f) ? val : -1.0f;
        // key: value-major, tie -> lower index wins (larger low word)
        keys[t] = ((u64)f2o(masked) << 32) | (u64)(0xFFFFFFFFu - (uint32_t)t);
    }
    if (t < NLOC) {
        int p = t;
        const float* lr; int local, hw, w; float is;
        if (p < 350)      { lr = l0; local = p;       hw = 350; w = 25; is = 16.0f; }
        else if (p < 441) { lr = l1; local = p - 350; hw = 91;  w = 13; is = 32.0f; }
        else              { lr = l2; local = p - 441; hw = 28;  w = 7;  is = 64.0f; }
        int y = local / w, x = local - y * w;
        float px = ((float)x + 0.5f) * is;
        float py = ((float)y + 0.5f) * is;
        float L = lr[local] * is;
        float T = lr[hw + local] * is;
        float R = lr[2 * hw + local] * is;
        float B = lr[3 * hw + local] * is;
        bbox[p] = make_float4(px - L, py - T, px + R, py + B);
    }
}

// rank[i] = #keys strictly greater than key[i]; split over 16 j-slices
__global__ void rank_kernel(const u64* __restrict__ keys, int* __restrict__ rank)
{
    __shared__ u64 tile[256];
    int t = blockIdx.x * blockDim.x + threadIdx.x;
    u64 myk = (t < NFLAT) ? keys[t] : 0xFFFFFFFFFFFFFFFFull;
    int begin = blockIdx.y * SLICE_LEN;
    int end = begin + SLICE_LEN;
    int cnt = 0;
    for (int base = begin; base < end; base += 256) {
        int j = base + threadIdx.x;
        tile[threadIdx.x] = (j < end) ? keys[j] : 0ull;
        __syncthreads();
        int lim = min(256, end - base);
        for (int q = 0; q < lim; ++q)
            cnt += (tile[q] > myk) ? 1 : 0;
        __syncthreads();
    }
    if (t < NFLAT && cnt > 0) atomicAdd(&rank[t], cnt);
}

__global__ void scatter_kernel(const u64* __restrict__ keys, const int* __restrict__ rank,
                               float* __restrict__ top_val, int* __restrict__ top_idx)
{
    int t = blockIdx.x * blockDim.x + threadIdx.x;
    if (t >= NFLAT) return;
    int r = rank[t];
    if (r < TOPK) {
        u64 k = keys[t];
        uint32_t o = (uint32_t)(k >> 32);
        uint32_t u = (o & 0x80000000u) ? (o ^ 0x80000000u) : ~o;  // inverse of f2o
        top_val[r] = __uint_as_float(u);
        top_idx[r] = (int)(0xFFFFFFFFu - (uint32_t)(k & 0xFFFFFFFFu));
    }
}

// Gather top boxes, compute global coord max, offset boxes + areas + valid bitmask.
__global__ void __launch_bounds__(1024) prep_kernel(
    const float* __restrict__ top_val, const int* __restrict__ top_idx,
    const float4* __restrict__ bbox,
    float4* __restrict__ sbox, float* __restrict__ sarea,
    u64* __restrict__ validw)
{
    __shared__ float swave[16];
    int j = threadIdx.x;
    bool active = j < TOPK;
    float4 b = make_float4(0.f, 0.f, 0.f, 0.f);
    float tv = -1.0f; int lab = 0;
    if (active) {
        tv = top_val[j];
        int idx = top_idx[j];
        int p = idx / NCLS;
        lab = idx - p * NCLS;
        b = bbox[p];
    }
    float m = active ? fmaxf(fmaxf(b.x, b.y), fmaxf(b.z, b.w)) : -3.0e38f;
    for (int o = 32; o > 0; o >>= 1) m = fmaxf(m, __shfl_down(m, o, 64));
    if ((j & 63) == 0) swave[j >> 6] = m;
    __syncthreads();
    if (j == 0) {
        float mm = swave[0];
        for (int q = 1; q < 16; ++q) mm = fmaxf(mm, swave[q]);
        swave[0] = mm;
    }
    __syncthreads();
    float off = (float)lab * (swave[0] + 1.0f);
    float4 s = make_float4(b.x + off, b.y + off, b.z + off, b.w + off);
    float area = fmaxf(s.z - s.x, 0.f) * fmaxf(s.w - s.y, 0.f);
    if (active) { sbox[j] = s; sarea[j] = area; }
    u64 bal = __ballot(active && (tv >= 0.05f));
    if ((j & 63) == 0) validw[j >> 6] = bal;
}

// Suppression matrix: mask[i*16+w] bit (j-w*64) set iff j>i and iou(i,j)>0.6
__global__ void mask_kernel(const float4* __restrict__ sbox, const float* __restrict__ sarea,
                            u64* __restrict__ mask)
{
    int g = blockIdx.x * 256 + threadIdx.x;
    if (g >= TOPK * NWORD) return;
    int i = g >> 4, w = g & 15;
    float4 si = sbox[i]; float ai = sarea[i];
    int j0 = w * 64, j1 = min(j0 + 64, TOPK);
    u64 bits = 0;
    for (int j = max(j0, i + 1); j < j1; ++j) {
        float4 sj = sbox[j];
        float ltx = fmaxf(si.x, sj.x), lty = fmaxf(si.y, sj.y);
        float rbx = fminf(si.z, sj.z), rby = fminf(si.w, sj.w);
        float iw = fmaxf(rbx - ltx, 0.f), ih = fmaxf(rby - lty, 0.f);
        float inter = iw * ih;
        float iou = inter / fmaxf(ai + sarea[j] - inter, 1e-9f);
        if (iou > 0.6f) bits |= 1ull << (j - j0);
    }
    mask[g] = bits;
}

// Single-wave greedy scan over the bitmask (no barriers in the sequential part),
// then all threads write outputs.
__global__ void __launch_bounds__(1024) scan_out_kernel(
    const u64* __restrict__ mask, const u64* __restrict__ validw,
    const float* __restrict__ top_val, const int* __restrict__ top_idx,
    const float4* __restrict__ bbox, float* __restrict__ out)
{
    __shared__ u64 smask[TOPK * NWORD];  // 128000 B
    __shared__ u64 skeep[NWORD];
    int tid = threadIdx.x;
    for (int g = tid; g < TOPK * NWORD; g += 1024) smask[g] = mask[g];
    __syncthreads();
    if (tid < 64) {
        int lane = tid;
        u64 sup = 0;   // lane l (l<16) owns suppressed word l
        for (int c = 0; c < NWORD; ++c) {
            u64 cur = __shfl(sup, c, 64);   // suppressed bits of chunk c
            u64 vw = validw[c];             // uniform
            u64 kw = 0;
            int nb = min(64, TOPK - c * 64);
            for (int b = 0; b < nb; ++b) {
                int i = c * 64 + b;
                u64 r  = smask[i * NWORD + (lane & 15)]; // unconditional
                u64 rc = smask[i * NWORD + c];           // broadcast
                bool kp = ((vw >> b) & 1ull) && !((cur >> b) & 1ull);   // uniform
                if (kp) {
                    cur |= rc;
                    if (lane < 16) sup |= r;
                    kw |= 1ull << b;
                }
            }
            if (lane == 0) skeep[c] = kw;
        }
    }
    __syncthreads();
    int j = tid;
    if (j < TOPK) {
        float tv = top_val[j];
        int idx = top_idx[j];
        int p = idx / NCLS;
        int lab = idx - p * NCLS;
        float4 b = bbox[p];
        bool kp = (skeep[j >> 6] >> (j & 63)) & 1ull;
        float x1 = fminf(fmaxf(b.x, 0.f), 224.f);
        float y1 = fminf(fmaxf(b.y, 0.f), 398.f);
        float x2 = fminf(fmaxf(b.z, 0.f), 224.f);
        float y2 = fminf(fmaxf(b.w, 0.f), 398.f);
        kp = kp && ((x2 - x1) >= 1e-5f) && ((y2 - y1) >= 1e-5f);
        out[j * 4 + 0] = kp ? x1 : 0.f;
        out[j * 4 + 1] = kp ? y1 : 0.f;
        out[j * 4 + 2] = kp ? x2 : 0.f;
        out[j * 4 + 3] = kp ? y2 : 0.f;
        out[4 * TOPK + j] = kp ? tv : -1.0f;
        out[5 * TOPK + j] = (float)lab;
        out[6 * TOPK + j] = kp ? 1.0f : 0.0f;
    }
}

extern "C" void kernel_launch(void* const* d_in, const int* in_sizes, int n_in,
                              void* d_out, int out_size, void* d_ws, size_t ws_size,
                              hipStream_t stream)
{
    const float* s0 = (const float*)d_in[0];
    const float* l0 = (const float*)d_in[1];
    const float* c0 = (const float*)d_in[2];
    const float* s1 = (const float*)d_in[3];
    const float* l1 = (const float*)d_in[4];
    const float* c1 = (const float*)d_in[5];
    const float* s2 = (const float*)d_in[6];
    const float* l2 = (const float*)d_in[7];
    const float* c2 = (const float*)d_in[8];

    uint8_t* ws = (uint8_t*)d_ws;
    u64*    keys  = (u64*)   (ws);                 // 37520*8  = 300160 B
    float4* bbox  = (float4*)(ws + 300160);        // 469*16   =   7504 B
    int*    rank  = (int*)   (ws + 307664);        // 37520*4  = 150080 B
    u64*    mask  = (u64*)   (ws + 307664);        // aliases rank (dead after scatter): 16000*8 = 128000 B
    float*  tval  = (float*) (ws + 457744);        // 1000*4
    int*    tidx  = (int*)   (ws + 461744);        // 1000*4
    float4* sbox  = (float4*)(ws + 465744);        // 1000*16
    float*  sarea = (float*) (ws + 481744);        // 1000*4
    u64*    validw = (u64*)  (ws + 485744);        // 16*8 -> total 485872 B

    decode_kernel<<<dim3((NFLAT + 255) / 256), 256, 0, stream>>>(
        s0, l0, c0, s1, l1, c1, s2, l2, c2, keys, bbox, rank);
    rank_kernel<<<dim3((NFLAT + 255) / 256, NSLICE), 256, 0, stream>>>(keys, rank);
    scatter_kernel<<<dim3((NFLAT + 255) / 256), 256, 0, stream>>>(keys, rank, tval, tidx);
    prep_kernel<<<1, 1024, 0, stream>>>(tval, tidx, bbox, sbox, sarea, validw);
    mask_kernel<<<dim3((TOPK * NWORD + 255) / 256), 256, 0, stream>>>(sbox, sarea, mask);
    scan_out_kernel<<<1, 1024, 0, stream>>>(mask, validw, tval, tidx, bbox, (float*)d_out);
}

// Round 4
// 182.301 us; speedup vs baseline: 2.3693x; 1.1685x over previous
//
#include <hip/hip_runtime.h>
#include <stdint.h>

#define NLOC 469
#define NCLS 80
#define NFLAT 37520
#define TOPK 1000
#define NWORD 16         // 1000 bits -> 16 uint64 words
#define NBIN 32768       // 15-bit histogram over key top bits
#define CAP 4096         // candidate capacity

typedef unsigned long long u64;

__device__ __forceinline__ float sigm(float x) { return 1.0f / (1.0f + expf(-x)); }

// order-preserving float -> uint32 (greater float => greater uint)
__device__ __forceinline__ uint32_t f2o(float f) {
    uint32_t u = __float_as_uint(f);
    return (u & 0x80000000u) ? ~u : (u | 0x80000000u);
}

// ---------------------------------------------------------------- decode + hist
__global__ void decode_kernel(
    const float* __restrict__ s0, const float* __restrict__ l0, const float* __restrict__ c0,
    const float* __restrict__ s1, const float* __restrict__ l1, const float* __restrict__ c1,
    const float* __restrict__ s2, const float* __restrict__ l2, const float* __restrict__ c2,
    u64* __restrict__ keys, float4* __restrict__ bbox, int* __restrict__ hist)
{
    int t = blockIdx.x * blockDim.x + threadIdx.x;
    if (t < NFLAT) {
        int p = t / NCLS;
        int k = t - p * NCLS;
        int c = k + 1;                       // class channel (0 = background, dropped)
        const float* sr; const float* cr; int local, hw;
        if (p < 350)      { sr = s0; cr = c0; local = p;       hw = 350; }
        else if (p < 441) { sr = s1; cr = c1; local = p - 350; hw = 91;  }
        else              { sr = s2; cr = c2; local = p - 441; hw = 28;  }
        float val = sqrtf(sigm(sr[c * hw + local]) * sigm(cr[local]));
        float masked = (val >= 0.05f) ? val : -1.0f;
        // key: value-major, tie -> lower index wins (larger low word)
        u64 key = ((u64)f2o(masked) << 32) | (u64)(0xFFFFFFFFu - (uint32_t)t);
        keys[t] = key;
        atomicAdd(&hist[(int)(key >> 49)], 1);   // bin = top 15 bits; bin order == key order
    }
    if (t < NLOC) {
        int p = t;
        const float* lr; int local, hw, w; float is;
        if (p < 350)      { lr = l0; local = p;       hw = 350; w = 25; is = 16.0f; }
        else if (p < 441) { lr = l1; local = p - 350; hw = 91;  w = 13; is = 32.0f; }
        else              { lr = l2; local = p - 441; hw = 28;  w = 7;  is = 64.0f; }
        int y = local / w, x = local - y * w;
        float px = ((float)x + 0.5f) * is;
        float py = ((float)y + 0.5f) * is;
        float L = lr[local] * is;
        float T = lr[hw + local] * is;
        float R = lr[2 * hw + local] * is;
        float B = lr[3 * hw + local] * is;
        bbox[p] = make_float4(px - L, py - T, px + R, py + B);
    }
}

// ------------------------------------------------- select cutoff bin + extract
__global__ void __launch_bounds__(1024) selext_kernel(
    const u64* __restrict__ keys, const int* __restrict__ hist,
    u64* __restrict__ cand, int* __restrict__ ctrl)
{
    __shared__ int scanbuf[1024];
    __shared__ int bstar_s;
    __shared__ int cnt_s;
    int tid = threadIdx.x;
    // thread tid owns bins [base, base+32), tid=0 has the HIGHEST bins
    int base = NBIN - 32 * (tid + 1);
    int gsum = 0;
    #pragma unroll
    for (int k = 0; k < 32; ++k) gsum += hist[base + k];
    scanbuf[tid] = gsum;
    __syncthreads();
    // Hillis-Steele inclusive scan (threads < tid == higher bins)
    for (int off = 1; off < 1024; off <<= 1) {
        int v = (tid >= off) ? scanbuf[tid - off] : 0;
        __syncthreads();
        scanbuf[tid] += v;
        __syncthreads();
    }
    int incl = scanbuf[tid];
    int cumAbove = incl - gsum;
    if (cumAbove < TOPK && incl >= TOPK) {   // exactly one thread
        int running = cumAbove;
        for (int k = 31; k >= 0; --k) {      // walk bins descending
            int b = base + k;
            int c = hist[b];
            if (running + c >= TOPK) { bstar_s = b; break; }
            running += c;
        }
    }
    if (tid == 0) cnt_s = 0;
    __syncthreads();
    int Bstar = bstar_s;
    for (int t = tid; t < NFLAT; t += 1024) {
        u64 k = keys[t];
        if ((int)(k >> 49) >= Bstar) {
            int pos = atomicAdd(&cnt_s, 1);
            if (pos < CAP) cand[pos] = k;
        }
    }
    __syncthreads();
    if (tid == 0) ctrl[0] = min(cnt_s, CAP);
}

// ------------------------------------------- exact ranking among candidates
__global__ void candrank_kernel(const u64* __restrict__ cand, const int* __restrict__ ctrl,
                                float* __restrict__ top_val, int* __restrict__ top_idx)
{
    __shared__ u64 tile[256];
    __shared__ int Cs;
    if (threadIdx.x == 0) Cs = ctrl[0];
    __syncthreads();
    int C = Cs;
    int c = blockIdx.x * 256 + threadIdx.x;
    u64 myk = (c < C) ? cand[c] : 0ull;
    int cnt = 0;
    for (int basej = 0; basej < C; basej += 256) {
        int j = basej + threadIdx.x;
        tile[threadIdx.x] = (j < C) ? cand[j] : 0ull;
        __syncthreads();
        int lim = min(256, C - basej);
        for (int q = 0; q < lim; ++q)
            cnt += (tile[q] > myk) ? 1 : 0;
        __syncthreads();
    }
    if (c < C && cnt < TOPK) {
        uint32_t o = (uint32_t)(myk >> 32);
        uint32_t u = (o & 0x80000000u) ? (o ^ 0x80000000u) : ~o;  // inverse of f2o
        top_val[cnt] = __uint_as_float(u);
        top_idx[cnt] = (int)(0xFFFFFFFFu - (uint32_t)(myk & 0xFFFFFFFFu));
    }
}

// --------------------------- per-block redundant prep + suppression-matrix build
__global__ void maskprep_kernel(const int* __restrict__ top_idx,
                                const float4* __restrict__ bbox,
                                u64* __restrict__ mask)
{
    __shared__ float4 sboxL[TOPK];   // 16000 B
    __shared__ float sareaL[TOPK];
    __shared__ int   labL[TOPK];
    __shared__ float redL[4];
    int tid = threadIdx.x;
    float m = -3.0e38f;
    for (int j = tid; j < TOPK; j += 256) {
        int idx = top_idx[j];
        int p = idx / NCLS;
        int lab = idx - p * NCLS;
        float4 b = bbox[p];
        sboxL[j] = b; labL[j] = lab;
        m = fmaxf(m, fmaxf(fmaxf(b.x, b.y), fmaxf(b.z, b.w)));
    }
    for (int o = 32; o > 0; o >>= 1) m = fmaxf(m, __shfl_down(m, o, 64));
    if ((tid & 63) == 0) redL[tid >> 6] = m;
    __syncthreads();
    float Mp1 = fmaxf(fmaxf(redL[0], redL[1]), fmaxf(redL[2], redL[3])) + 1.0f;
    for (int j = tid; j < TOPK; j += 256) {
        float off = (float)labL[j] * Mp1;
        float4 b = sboxL[j];
        float4 s = make_float4(b.x + off, b.y + off, b.z + off, b.w + off);
        sboxL[j] = s;
        sareaL[j] = fmaxf(s.z - s.x, 0.f) * fmaxf(s.w - s.y, 0.f);
    }
    __syncthreads();
    int g = blockIdx.x * 256 + tid;
    if (g < TOPK * NWORD) {
        int i = g >> 4, w = g & 15;
        float4 si = sboxL[i]; float ai = sareaL[i];
        int j0 = w * 64, j1 = min(j0 + 64, TOPK);
        u64 bits = 0;
        for (int j = max(j0, i + 1); j < j1; ++j) {
            float4 sj = sboxL[j];
            float ltx = fmaxf(si.x, sj.x), lty = fmaxf(si.y, sj.y);
            float rbx = fminf(si.z, sj.z), rby = fminf(si.w, sj.w);
            float iw = fmaxf(rbx - ltx, 0.f), ih = fmaxf(rby - lty, 0.f);
            float inter = iw * ih;
            float iou = inter / fmaxf(ai + sareaL[j] - inter, 1e-9f);
            if (iou > 0.6f) bits |= 1ull << (j - j0);
        }
        mask[g] = bits;
    }
}

// ------------------------------ greedy scan over bitmask + final output write
__global__ void __launch_bounds__(1024) scan_out_kernel(
    const u64* __restrict__ mask,
    const float* __restrict__ top_val, const int* __restrict__ top_idx,
    const float4* __restrict__ bbox, float* __restrict__ out)
{
    __shared__ u64 smask[TOPK * NWORD];  // 128000 B
    __shared__ u64 skeep[NWORD];
    __shared__ u64 validwL[NWORD];
    int tid = threadIdx.x;
    int j = tid;
    float tv = (j < TOPK) ? top_val[j] : -1.0f;
    u64 bal = __ballot(j < TOPK && tv >= 0.05f);
    if ((tid & 63) == 0) validwL[tid >> 6] = bal;
    for (int g = tid; g < TOPK * NWORD; g += 1024) smask[g] = mask[g];
    __syncthreads();
    if (tid < 64) {
        int lane = tid;
        u64 sup = 0;   // lane l (l<16) owns suppressed word l
        for (int c = 0; c < NWORD; ++c) {
            u64 cur = __shfl(sup, c, 64);   // suppressed bits of chunk c
            u64 vw = validwL[c];            // uniform
            u64 kw = 0;
            int nb = min(64, TOPK - c * 64);
            for (int b = 0; b < nb; ++b) {
                int i = c * 64 + b;
                u64 r  = smask[i * NWORD + (lane & 15)]; // unconditional
                u64 rc = smask[i * NWORD + c];           // broadcast
                bool kp = ((vw >> b) & 1ull) && !((cur >> b) & 1ull);   // uniform
                if (kp) {
                    cur |= rc;
                    if (lane < 16) sup |= r;
                    kw |= 1ull << b;
                }
            }
            if (lane == 0) skeep[c] = kw;
        }
    }
    __syncthreads();
    if (j < TOPK) {
        int idx = top_idx[j];
        int p = idx / NCLS;
        int lab = idx - p * NCLS;
        float4 b = bbox[p];
        bool kp = (skeep[j >> 6] >> (j & 63)) & 1ull;
        float x1 = fminf(fmaxf(b.x, 0.f), 224.f);
        float y1 = fminf(fmaxf(b.y, 0.f), 398.f);
        float x2 = fminf(fmaxf(b.z, 0.f), 224.f);
        float y2 = fminf(fmaxf(b.w, 0.f), 398.f);
        kp = kp && ((x2 - x1) >= 1e-5f) && ((y2 - y1) >= 1e-5f);
        out[j * 4 + 0] = kp ? x1 : 0.f;
        out[j * 4 + 1] = kp ? y1 : 0.f;
        out[j * 4 + 2] = kp ? x2 : 0.f;
        out[j * 4 + 3] = kp ? y2 : 0.f;
        out[4 * TOPK + j] = kp ? tv : -1.0f;
        out[5 * TOPK + j] = (float)lab;
        out[6 * TOPK + j] = kp ? 1.0f : 0.0f;
    }
}

extern "C" void kernel_launch(void* const* d_in, const int* in_sizes, int n_in,
                              void* d_out, int out_size, void* d_ws, size_t ws_size,
                              hipStream_t stream)
{
    const float* s0 = (const float*)d_in[0];
    const float* l0 = (const float*)d_in[1];
    const float* c0 = (const float*)d_in[2];
    const float* s1 = (const float*)d_in[3];
    const float* l1 = (const float*)d_in[4];
    const float* c1 = (const float*)d_in[5];
    const float* s2 = (const float*)d_in[6];
    const float* l2 = (const float*)d_in[7];
    const float* c2 = (const float*)d_in[8];

    uint8_t* ws = (uint8_t*)d_ws;
    u64*    keys = (u64*)   (ws);                 // 37520*8  = 300160 B
    float4* bbox = (float4*)(ws + 300160);        // 469*16   =   7504 B
    int*    hist = (int*)   (ws + 307664);        // 32768*4  = 131072 B (dead after selext)
    u64*    mask = (u64*)   (ws + 307664);        // aliases hist: 16000*8 = 128000 B
    u64*    cand = (u64*)   (ws + 438736);        // 4096*8   =  32768 B
    float*  tval = (float*) (ws + 471504);        // 1000*4
    int*    tidx = (int*)   (ws + 475504);        // 1000*4
    int*    ctrl = (int*)   (ws + 479504);        // 16 B -> total 479520 B

    hipMemsetAsync(hist, 0, NBIN * sizeof(int), stream);
    decode_kernel<<<dim3((NFLAT + 255) / 256), 256, 0, stream>>>(
        s0, l0, c0, s1, l1, c1, s2, l2, c2, keys, bbox, hist);
    selext_kernel<<<1, 1024, 0, stream>>>(keys, hist, cand, ctrl);
    candrank_kernel<<<dim3(CAP / 256), 256, 0, stream>>>(cand, ctrl, tval, tidx);
    maskprep_kernel<<<dim3((TOPK * NWORD + 255) / 256), 256, 0, stream>>>(tidx, bbox, mask);
    scan_out_kernel<<<1, 1024, 0, stream>>>(mask, tval, tidx, bbox, (float*)d_out);
}

// Round 5
// 116.335 us; speedup vs baseline: 3.7127x; 1.5670x over previous
//
#include <hip/hip_runtime.h>
#include <stdint.h>

#define NLOC 469
#define NCLS 80
#define NFLAT 37520
#define TOPK 1000
#define NWORD 16         // 1000 bits -> 16 uint64 words
#define NBIN 32768       // 15-bit histogram over key top bits
#define CAP 2048         // candidate capacity (LDS)

typedef unsigned long long u64;

__device__ __forceinline__ float sigm(float x) { return 1.0f / (1.0f + expf(-x)); }

// order-preserving float -> uint32 (greater float => greater uint)
__device__ __forceinline__ uint32_t f2o(float f) {
    uint32_t u = __float_as_uint(f);
    return (u & 0x80000000u) ? ~u : (u | 0x80000000u);
}

// ---------------------------------------------------------------- decode
__global__ void decode_kernel(
    const float* __restrict__ s0, const float* __restrict__ l0, const float* __restrict__ c0,
    const float* __restrict__ s1, const float* __restrict__ l1, const float* __restrict__ c1,
    const float* __restrict__ s2, const float* __restrict__ l2, const float* __restrict__ c2,
    u64* __restrict__ keys, float4* __restrict__ bbox)
{
    int t = blockIdx.x * blockDim.x + threadIdx.x;
    if (t < NFLAT) {
        int p = t / NCLS;
        int k = t - p * NCLS;
        int c = k + 1;                       // class channel (0 = background, dropped)
        const float* sr; const float* cr; int local, hw;
        if (p < 350)      { sr = s0; cr = c0; local = p;       hw = 350; }
        else if (p < 441) { sr = s1; cr = c1; local = p - 350; hw = 91;  }
        else              { sr = s2; cr = c2; local = p - 441; hw = 28;  }
        float val = sqrtf(sigm(sr[c * hw + local]) * sigm(cr[local]));
        float masked = (val >= 0.05f) ? val : -1.0f;
        // key: value-major, tie -> lower index wins (larger low word)
        keys[t] = ((u64)f2o(masked) << 32) | (u64)(0xFFFFFFFFu - (uint32_t)t);
    }
    if (t < NLOC) {
        int p = t;
        const float* lr; int local, hw, w; float is;
        if (p < 350)      { lr = l0; local = p;       hw = 350; w = 25; is = 16.0f; }
        else if (p < 441) { lr = l1; local = p - 350; hw = 91;  w = 13; is = 32.0f; }
        else              { lr = l2; local = p - 441; hw = 28;  w = 7;  is = 64.0f; }
        int y = local / w, x = local - y * w;
        float px = ((float)x + 0.5f) * is;
        float py = ((float)y + 0.5f) * is;
        float L = lr[local] * is;
        float T = lr[hw + local] * is;
        float R = lr[2 * hw + local] * is;
        float B = lr[3 * hw + local] * is;
        bbox[p] = make_float4(px - L, py - T, px + R, py + B);
    }
}

// ----------------------------------------- fused all-LDS top-k (1 block)
__global__ void __launch_bounds__(1024) topk_kernel(
    const u64* __restrict__ keys,
    float* __restrict__ top_val, int* __restrict__ top_idx)
{
    __shared__ int histL[NBIN];      // 128 KB: counts -> bin-start -> bin-end
    __shared__ int scanbuf[1024];    // 4 KB
    __shared__ u64 candL[CAP];       // 16 KB, bin-segmented after scatter
    __shared__ int bstar_s;
    int tid = threadIdx.x;
    for (int z = tid; z < NBIN; z += 1024) histL[z] = 0;
    __syncthreads();
    for (int t = tid; t < NFLAT; t += 1024)
        atomicAdd(&histL[(int)(keys[t] >> 49)], 1);
    __syncthreads();
    // thread tid owns bins [base, base+32); tid=0 owns the HIGHEST bins
    int base = NBIN - 32 * (tid + 1);
    int r[32];
    int gsum = 0;
    #pragma unroll
    for (int k = 0; k < 32; ++k) { r[k] = histL[base + k]; gsum += r[k]; }
    scanbuf[tid] = gsum;
    __syncthreads();
    for (int off = 1; off < 1024; off <<= 1) {   // Hillis-Steele inclusive scan
        int v = (tid >= off) ? scanbuf[tid - off] : 0;
        __syncthreads();
        scanbuf[tid] += v;
        __syncthreads();
    }
    int incl = scanbuf[tid];
    int cumAbove = incl - gsum;   // keys in bins above my range
    if (cumAbove < TOPK && incl >= TOPK) {       // exactly one thread crosses
        int running = cumAbove;
        #pragma unroll
        for (int k = 31; k >= 0; --k) {          // walk own bins descending (regs)
            if (running + r[k] >= TOPK) { bstar_s = base + k; break; }
            running += r[k];
        }
    }
    // in-place convert own bins to start offsets (descending bin-major layout)
    {
        int run = cumAbove;
        #pragma unroll
        for (int k = 31; k >= 0; --k) { histL[base + k] = run; run += r[k]; }
    }
    __syncthreads();
    int Bstar = bstar_s;
    // counting-sort scatter of candidates: cursors turn start(b) into end(b)
    for (int t = tid; t < NFLAT; t += 1024) {
        u64 k = keys[t];
        int b = (int)(k >> 49);
        if (b >= Bstar) {
            int pos = atomicAdd(&histL[b], 1);
            if (pos < CAP) candL[pos] = k;
        }
    }
    __syncthreads();
    int C = min(histL[Bstar], CAP);   // end(Bstar) == total candidate count
    // exact rank = segL (#cands in higher bins) + within-segment count
    for (int p = tid; p < C; p += 1024) {
        u64 k = candL[p];
        int b = (int)(k >> 49);
        int segL = (b == NBIN - 1) ? 0 : min(histL[b + 1], CAP);
        int segR = min(histL[b], CAP);
        int cnt = segL;
        for (int q = segL; q < segR; ++q)
            cnt += (candL[q] > k) ? 1 : 0;
        if (cnt < TOPK) {
            uint32_t o = (uint32_t)(k >> 32);
            uint32_t u = (o & 0x80000000u) ? (o ^ 0x80000000u) : ~o;  // inverse f2o
            top_val[cnt] = __uint_as_float(u);
            top_idx[cnt] = (int)(0xFFFFFFFFu - (uint32_t)(k & 0xFFFFFFFFu));
        }
    }
}

// --------------------------- per-block redundant prep + suppression matrix
__global__ void maskprep_kernel(const int* __restrict__ top_idx,
                                const float4* __restrict__ bbox,
                                u64* __restrict__ mask)
{
    __shared__ float4 sboxL[TOPK];   // 16000 B
    __shared__ float sareaL[TOPK];
    __shared__ int   labL[TOPK];
    __shared__ float redL[4];
    int tid = threadIdx.x;
    float m = -3.0e38f;
    for (int j = tid; j < TOPK; j += 256) {
        int idx = top_idx[j];
        int p = idx / NCLS;
        int lab = idx - p * NCLS;
        float4 b = bbox[p];
        sboxL[j] = b; labL[j] = lab;
        m = fmaxf(m, fmaxf(fmaxf(b.x, b.y), fmaxf(b.z, b.w)));
    }
    for (int o = 32; o > 0; o >>= 1) m = fmaxf(m, __shfl_down(m, o, 64));
    if ((tid & 63) == 0) redL[tid >> 6] = m;
    __syncthreads();
    float Mp1 = fmaxf(fmaxf(redL[0], redL[1]), fmaxf(redL[2], redL[3])) + 1.0f;
    for (int j = tid; j < TOPK; j += 256) {
        float off = (float)labL[j] * Mp1;
        float4 b = sboxL[j];
        float4 s = make_float4(b.x + off, b.y + off, b.z + off, b.w + off);
        sboxL[j] = s;
        sareaL[j] = fmaxf(s.z - s.x, 0.f) * fmaxf(s.w - s.y, 0.f);
    }
    __syncthreads();
    int g = blockIdx.x * 256 + tid;
    if (g < TOPK * NWORD) {
        int i = g >> 4, w = g & 15;
        float4 si = sboxL[i]; float ai = sareaL[i];
        int j0 = w * 64, j1 = min(j0 + 64, TOPK);
        u64 bits = 0;
        for (int j = max(j0, i + 1); j < j1; ++j) {
            float4 sj = sboxL[j];
            float ltx = fmaxf(si.x, sj.x), lty = fmaxf(si.y, sj.y);
            float rbx = fminf(si.z, sj.z), rby = fminf(si.w, sj.w);
            float iw = fmaxf(rbx - ltx, 0.f), ih = fmaxf(rby - lty, 0.f);
            float inter = iw * ih;
            float iou = inter / fmaxf(ai + sareaL[j] - inter, 1e-9f);
            if (iou > 0.6f) bits |= 1ull << (j - j0);
        }
        mask[g] = bits;
    }
}

// ------------------ pipelined greedy scan over bitmask + final output write
__global__ void __launch_bounds__(1024) scan_out_kernel(
    const u64* __restrict__ mask,
    const float* __restrict__ top_val, const int* __restrict__ top_idx,
    const float4* __restrict__ bbox, float* __restrict__ out)
{
    __shared__ u64 smask[TOPK * NWORD];  // 128000 B
    __shared__ u64 skeep[NWORD];
    __shared__ u64 validwL[NWORD];
    int tid = threadIdx.x;
    float tv = (tid < TOPK) ? top_val[tid] : -1.0f;
    u64 bal = __ballot(tid < TOPK && tv >= 0.05f);
    if ((tid & 63) == 0) validwL[tid >> 6] = bal;
    for (int g = tid; g < TOPK * NWORD; g += 1024) smask[g] = mask[g];
    __syncthreads();
    if (tid < 64) {
        int lane = tid;
        int lw = lane & 15;
        u64 sup = 0;                         // lanes 0-15: suppressed word lw
        u64 r_next = smask[lw];              // prefetch row 0
        for (int c = 0; c < NWORD; ++c) {
            u64 cur = __shfl(sup, c, 64);    // suppressed bits of chunk c
            u64 vw = validwL[c];
            u64 kw = 0;
            u64 rc_next = smask[(c * 64) * NWORD + c];
            int nb = min(64, TOPK - c * 64);
            for (int b = 0; b < nb; ++b) {
                int i = c * 64 + b;
                u64 r  = r_next;             // row i, word lw (prefetched)
                u64 rc = rc_next;            // row i, word c  (prefetched)
                int inext = i + 1;
                if (inext < TOPK) {          // prefetch next row (off critical path)
                    r_next  = smask[inext * NWORD + lw];
                    rc_next = smask[inext * NWORD + c];
                }
                u64 bit = 1ull << b;
                bool kp = (vw & bit) && !(cur & bit);   // uniform across lanes
                if (kp) {
                    cur |= rc;
                    sup |= r;
                    kw |= bit;
                }
            }
            if (lane == 0) skeep[c] = kw;
        }
    }
    __syncthreads();
    int j = tid;
    if (j < TOPK) {
        int idx = top_idx[j];
        int p = idx / NCLS;
        int lab = idx - p * NCLS;
        float4 b = bbox[p];
        bool kp = (skeep[j >> 6] >> (j & 63)) & 1ull;
        float x1 = fminf(fmaxf(b.x, 0.f), 224.f);
        float y1 = fminf(fmaxf(b.y, 0.f), 398.f);
        float x2 = fminf(fmaxf(b.z, 0.f), 224.f);
        float y2 = fminf(fmaxf(b.w, 0.f), 398.f);
        kp = kp && ((x2 - x1) >= 1e-5f) && ((y2 - y1) >= 1e-5f);
        out[j * 4 + 0] = kp ? x1 : 0.f;
        out[j * 4 + 1] = kp ? y1 : 0.f;
        out[j * 4 + 2] = kp ? x2 : 0.f;
        out[j * 4 + 3] = kp ? y2 : 0.f;
        out[4 * TOPK + j] = kp ? tv : -1.0f;
        out[5 * TOPK + j] = (float)lab;
        out[6 * TOPK + j] = kp ? 1.0f : 0.0f;
    }
}

extern "C" void kernel_launch(void* const* d_in, const int* in_sizes, int n_in,
                              void* d_out, int out_size, void* d_ws, size_t ws_size,
                              hipStream_t stream)
{
    const float* s0 = (const float*)d_in[0];
    const float* l0 = (const float*)d_in[1];
    const float* c0 = (const float*)d_in[2];
    const float* s1 = (const float*)d_in[3];
    const float* l1 = (const float*)d_in[4];
    const float* c1 = (const float*)d_in[5];
    const float* s2 = (const float*)d_in[6];
    const float* l2 = (const float*)d_in[7];
    const float* c2 = (const float*)d_in[8];

    uint8_t* ws = (uint8_t*)d_ws;
    u64*    keys = (u64*)   (ws);              // 37520*8  = 300160 B
    float4* bbox = (float4*)(ws + 300160);     // 469*16   =   7504 B
    u64*    mask = (u64*)   (ws + 307664);     // 16000*8  = 128000 B
    float*  tval = (float*) (ws + 435664);     // 1000*4
    int*    tidx = (int*)   (ws + 439664);     // 1000*4  -> 443664 B total

    decode_kernel<<<dim3((NFLAT + 255) / 256), 256, 0, stream>>>(
        s0, l0, c0, s1, l1, c1, s2, l2, c2, keys, bbox);
    topk_kernel<<<1, 1024, 0, stream>>>(keys, tval, tidx);
    maskprep_kernel<<<dim3((TOPK * NWORD + 255) / 256), 256, 0, stream>>>(tidx, bbox, mask);
    scan_out_kernel<<<1, 1024, 0, stream>>>(mask, tval, tidx, bbox, (float*)d_out);
}